// Round 12
// baseline (273.127 us; speedup 1.0000x reference)
//
#include <hip/hip_runtime.h>

#define D 128
#define NH 8
#define BCAP 64   // per-node edge bucket capacity (E/N=8, Poisson tail << 64)

typedef __bf16 bf16x8 __attribute__((ext_vector_type(8)));
typedef unsigned short ushortx8 __attribute__((ext_vector_type(8)));
typedef float floatx4 __attribute__((ext_vector_type(4)));

__device__ __forceinline__ float bf2f(unsigned short u) {
  union { unsigned int i; float f; } x; x.i = ((unsigned int)u) << 16; return x.f;
}
__device__ __forceinline__ unsigned short f2bf(float f) {
  union { float f; unsigned int i; } x; x.f = f;
  unsigned int i = x.i;
  return (unsigned short)((i + 0x7FFFu + ((i >> 16) & 1u)) >> 16);
}
__device__ __forceinline__ void acc2(unsigned int ku, unsigned int qu, float& s) {
  union { unsigned int i; float f; } a, b;
  a.i = ku << 16;          b.i = qu << 16;          s += a.f * b.f;
  a.i = ku & 0xffff0000u;  b.i = qu & 0xffff0000u;  s += a.f * b.f;
}

// =============== phase helpers (proven bodies) ==============================
// weight fold: p0 Wk ; p1 Wq.rel_attT * pri*2.5 ; p2..4 Wq.wm_mT ; p5 Wv.rel_msg
// p6 = Wa^T bf16 (consumed by the fused node+out GEMM).
__device__ __forceinline__ void fold_item(
    int gid,
    const float* __restrict__ Wk, const float* __restrict__ bk,
    const float* __restrict__ Wq, const float* __restrict__ bq,
    const float* __restrict__ Wv, const float* __restrict__ bv,
    const float* __restrict__ Wa,
    const float* __restrict__ rel_att, const float* __restrict__ rel_msg,
    const float* __restrict__ rel_pri,
    const float* __restrict__ wm0, const float* __restrict__ wm1,
    const float* __restrict__ wm2,
    unsigned short* __restrict__ Wt_all, float* __restrict__ bias_all)
{
  int p = gid >> 14;
  int idx = gid & 16383;
  int c = idx >> 7, k = idx & 127;
  int h = c >> 4, r = c & 15;
  float wsum = 0.f, bsum = 0.f;
  if (p == 0) {
    wsum = Wk[k * 128 + c];
    bsum = bk[c];
  } else if (p <= 4) {
    const float* M = (p == 1) ? rel_att : ((p == 2) ? wm0 : ((p == 3) ? wm1 : wm2));
#pragma unroll
    for (int f = 0; f < 16; f++) {
      float mv = M[h * 256 + r * 16 + f];
      wsum += Wq[k * 128 + h * 16 + f] * mv;
      bsum += bq[h * 16 + f] * mv;
    }
    if (p == 1) { float sc = rel_pri[h] * 2.5f; wsum *= sc; bsum *= sc; }
  } else if (p == 5) {
#pragma unroll
    for (int d = 0; d < 16; d++) {
      float mv = rel_msg[h * 256 + d * 16 + r];
      wsum += Wv[k * 128 + h * 16 + d] * mv;
      bsum += bv[h * 16 + d] * mv;
    }
  } else {            // p == 6: Wa^T bf16
    wsum = Wa[k * 128 + c];
    bsum = 0.f;
  }
  Wt_all[(size_t)p * 16384 + c * 128 + k] = f2bf(wsum);
  if (k == 0) bias_all[p * 128 + c] = bsum;
}

// one 64-row x 4-plane projection tile, 256 threads.
// r12: NO LDS staging — B-fragments read DIRECTLY from Wt_all (L2-resident,
// identical across all 939 blocks; staging read the same bytes through L2
// anyway). Deletes all 8 barriers/block. Swapped MFMA epilogue (r8): lane
// owns P[row0+l16][ct2*16+quad*4..+3] -> dwordx2 stores.
__device__ __forceinline__ void proj_tile(
    int t, const float* __restrict__ x0, const float* __restrict__ x1,
    const float* __restrict__ x2,
    const unsigned short* __restrict__ Wt_all, const float* __restrict__ bias_all,
    unsigned short* __restrict__ P, int N, int tid)
{
  int m = t % 3, rt = t / 3;
  const float* X = (m == 0) ? x0 : ((m == 1) ? x1 : x2);
  int wave = tid >> 6, lane = tid & 63;
  int quad = lane >> 4, l16 = lane & 15;
  int row0 = rt * 64 + wave * 16;
  int arow = row0 + l16; if (arow >= N) arow = N - 1;
  const float* ap = X + (size_t)arow * D;
  bf16x8 afr[4];
#pragma unroll
  for (int kk4 = 0; kk4 < 4; kk4++) {
    float4 f0 = *(const float4*)(ap + kk4 * 32 + quad * 8);
    float4 f1 = *(const float4*)(ap + kk4 * 32 + quad * 8 + 4);
    ushortx8 uu;
    uu[0]=f2bf(f0.x); uu[1]=f2bf(f0.y); uu[2]=f2bf(f0.z); uu[3]=f2bf(f0.w);
    uu[4]=f2bf(f1.x); uu[5]=f2bf(f1.y); uu[6]=f2bf(f1.z); uu[7]=f2bf(f1.w);
    afr[kk4] = __builtin_bit_cast(bf16x8, uu);
  }
  int r = row0 + l16;                       // this lane's output row (swapped)
  for (int pt = 0; pt < 4; pt++) {
    int wp = (pt == 0) ? 0 : ((pt == 1) ? 1 : ((pt == 2) ? (2 + m) : 5));
    const unsigned short* Wsrc = Wt_all + (size_t)wp * 16384;
    const float* B = bias_all + wp * 128;
    unsigned short* Pout = P + (size_t)(pt * 3 + m) * N * D;
    floatx4 acc[8];
#pragma unroll
    for (int ct = 0; ct < 8; ct++) acc[ct] = (floatx4)0.f;
#pragma unroll
    for (int kk4 = 0; kk4 < 4; kk4++) {
#pragma unroll
      for (int ct2 = 0; ct2 < 8; ct2++) {
        uint4 bu = *(const uint4*)(&Wsrc[(ct2 * 16 + l16) * 128 + kk4 * 32 + quad * 8]);
        bf16x8 bf = __builtin_bit_cast(bf16x8, bu);
        acc[ct2] =
            __builtin_amdgcn_mfma_f32_16x16x32_bf16(bf, afr[kk4], acc[ct2], 0, 0, 0);
      }
    }
    if (r < N) {
      unsigned short* Prow = Pout + (size_t)r * D;
#pragma unroll
      for (int ct2 = 0; ct2 < 8; ct2++) {
        int colb = ct2 * 16 + quad * 4;
        float4 bi = *(const float4*)(&B[colb]);
        unsigned int lo = ((unsigned int)f2bf(acc[ct2][1] + bi.y) << 16) |
                          f2bf(acc[ct2][0] + bi.x);
        unsigned int hi = ((unsigned int)f2bf(acc[ct2][3] + bi.w) << 16) |
                          f2bf(acc[ct2][2] + bi.z);
        uint2 pk; pk.x = lo; pk.y = hi;
        *(uint2*)(&Prow[colb]) = pk;
      }
    }
  }
}

// one dst node per wave — r4-proven body; fetch-traffic-bound at ~2.2TB/s
// random-gather ceiling (r6/r7 falsified occupancy and VMEM-count theories).
// Results go to the block's LDS Hs tile (row = m*4 + wave). Edges come from
// the fixed-capacity bucket (srcs = bucket + n*BCAP).
__device__ __forceinline__ void edge_vals(
    const unsigned short* __restrict__ P, size_t Nsz, int s, int h,
    const uint4 (&qa)[3][2], const uint4 (&qw)[3][2],
    float (&av)[3], float (&lv)[3])
{
#pragma unroll
  for (int m = 0; m < 3; m++) {
    const unsigned short* kp = P + ((size_t)m * Nsz + s) * 128 + h * 16;
    uint4 k0 = *(const uint4*)kp, k1 = *(const uint4*)(kp + 8);
    const unsigned int* ka = (const unsigned int*)&k0;
    const unsigned int* kb = (const unsigned int*)&k1;
    const unsigned int* a0 = (const unsigned int*)&qa[m][0];
    const unsigned int* a1 = (const unsigned int*)&qa[m][1];
    const unsigned int* w0 = (const unsigned int*)&qw[m][0];
    const unsigned int* w1 = (const unsigned int*)&qw[m][1];
    float da = 0.f, dw = 0.f;
#pragma unroll
    for (int j = 0; j < 4; j++) {
      acc2(ka[j], a0[j], da); acc2(kb[j], a1[j], da);
      acc2(ka[j], w0[j], dw); acc2(kb[j], w1[j], dw);
    }
    av[m] = da;
    lv[m] = dw;
  }
  float mx = fmaxf(lv[0], fmaxf(lv[1], lv[2]));
  float e0 = __expf(lv[0] - mx), e1 = __expf(lv[1] - mx), e2 = __expf(lv[2] - mx);
  float inv = 1.f / (e0 + e1 + e2);
  lv[0] = e0 * inv; lv[1] = e1 * inv; lv[2] = e2 * inv;
}

__device__ __forceinline__ void node_one(
    int n, const unsigned short* __restrict__ P,
    const int* __restrict__ counts, const int* __restrict__ bucket,
    unsigned short* __restrict__ Hs,
    int N, int lane, int wave)
{
  const int* srcs = bucket + (size_t)n * BCAP;
  int deg = counts[n]; if (deg > BCAP) deg = BCAP;
  float acc00 = 0, acc01 = 0, acc10 = 0, acc11 = 0, acc20 = 0, acc21 = 0;
  if (deg > 0) {
    int h = lane & 7, slot = lane >> 3;
    size_t Nsz = (size_t)N;
    uint4 qa[3][2], qw[3][2];
#pragma unroll
    for (int m = 0; m < 3; m++) {
      const unsigned short* qap = P + ((size_t)(3 + m) * Nsz + n) * 128 + h * 16;
      const unsigned short* qwp = P + ((size_t)(6 + m) * Nsz + n) * 128 + h * 16;
      qa[m][0] = *(const uint4*)qap; qa[m][1] = *(const uint4*)(qap + 8);
      qw[m][0] = *(const uint4*)qwp; qw[m][1] = *(const uint4*)(qwp + 8);
    }
    int nch = (deg + 7) >> 3;
    float cX0[4] = {}, cX1[4] = {}, cX2[4] = {}, cEa[4] = {}, cT[4] = {};
    int cS[4] = {};
    float sA0 = 0, sA1 = 0, sA2 = 0, sAl = 0;
#pragma unroll
    for (int c = 0; c < 4; c++) {
      int idx = c * 8 + slot;
      if (c < nch && idx < deg) {
        int s = srcs[idx]; cS[c] = s;
        float av[3], lv[3];
        edge_vals(P, Nsz, s, h, qa, qw, av, lv);
        float e0 = __expf(av[0]), e1 = __expf(av[1]), e2 = __expf(av[2]);
        float align = -(fabsf(av[0]-av[1]) + fabsf(av[0]-av[2]) + fabsf(av[1]-av[2])) * (1.f/3.f);
        float ea = __expf(align);
        cX0[c] = lv[0] * e0; cX1[c] = lv[1] * e1; cX2[c] = lv[2] * e2; cEa[c] = ea;
        sA0 += e0; sA1 += e1; sA2 += e2; sAl += ea;
      }
    }
    for (int c = 4; c < nch; c++) {
      int idx = c * 8 + slot;
      if (idx < deg) {
        int s = srcs[idx];
        float av[3], lv[3];
        edge_vals(P, Nsz, s, h, qa, qw, av, lv);
        float align = -(fabsf(av[0]-av[1]) + fabsf(av[0]-av[2]) + fabsf(av[1]-av[2])) * (1.f/3.f);
        sA0 += __expf(av[0]); sA1 += __expf(av[1]); sA2 += __expf(av[2]);
        sAl += __expf(align);
      }
    }
#pragma unroll
    for (int off = 8; off < 64; off <<= 1) {
      sA0 += __shfl_xor(sA0, off, 64);
      sA1 += __shfl_xor(sA1, off, 64);
      sA2 += __shfl_xor(sA2, off, 64);
      sAl += __shfl_xor(sAl, off, 64);
    }
    float rA0 = 1.f / fmaxf(sA0, 1e-30f), rA1 = 1.f / fmaxf(sA1, 1e-30f);
    float rA2 = 1.f / fmaxf(sA2, 1e-30f), rAl = 1.f / fmaxf(sAl, 1e-30f);
    float sT = 0;
#pragma unroll
    for (int c = 0; c < 4; c++) {
      int idx = c * 8 + slot;
      if (c < nch && idx < deg) {
        float t = (cX0[c] * rA0 + cX1[c] * rA1 + cX2[c] * rA2) * (cEa[c] * rAl);
        cT[c] = t;
        sT += __expf(t);
      }
    }
    for (int c = 4; c < nch; c++) {
      int idx = c * 8 + slot;
      if (idx < deg) {
        int s = srcs[idx];
        float av[3], lv[3];
        edge_vals(P, Nsz, s, h, qa, qw, av, lv);
        float align = -(fabsf(av[0]-av[1]) + fabsf(av[0]-av[2]) + fabsf(av[1]-av[2])) * (1.f/3.f);
        float t = (lv[0]*__expf(av[0])*rA0 + lv[1]*__expf(av[1])*rA1 + lv[2]*__expf(av[2])*rA2)
                  * (__expf(align) * rAl);
        sT += __expf(t);
      }
    }
#pragma unroll
    for (int off = 8; off < 64; off <<= 1) sT += __shfl_xor(sT, off, 64);
    float rT = 1.f / fmaxf(sT, 1e-30f);
    const unsigned int* Pu = (const unsigned int*)P;
    int hl = lane >> 3;
#pragma unroll
    for (int c = 0; c < 4; c++) {
      if (c < nch) {
        int idx = c * 8 + slot;
        float beta = (idx < deg) ? __expf(cT[c]) * rT : 0.f;
        int sv = cS[c];
        float bj[8]; int sj[8];
#pragma unroll
        for (int jj = 0; jj < 8; jj++) {
          bj[jj] = __shfl(beta, jj * 8 + hl, 64);
          sj[jj] = __shfl(sv, jj * 8, 64);
        }
#pragma unroll
        for (int jj = 0; jj < 8; jj++) {
          size_t base9 = ((size_t)9 * Nsz + sj[jj]) * 64 + lane;
          unsigned int u0 = Pu[base9];
          unsigned int u1 = Pu[base9 + Nsz * 64];
          unsigned int u2 = Pu[base9 + 2 * Nsz * 64];
          float b = bj[jj];
          acc00 += b * bf2f((unsigned short)u0); acc01 += b * bf2f((unsigned short)(u0 >> 16));
          acc10 += b * bf2f((unsigned short)u1); acc11 += b * bf2f((unsigned short)(u1 >> 16));
          acc20 += b * bf2f((unsigned short)u2); acc21 += b * bf2f((unsigned short)(u2 >> 16));
        }
      }
    }
    for (int c = 4; c < nch; c++) {
      int idx = c * 8 + slot;
      float beta = 0.f; int sv = 0;
      if (idx < deg) {
        sv = srcs[idx];
        float av[3], lv[3];
        edge_vals(P, Nsz, sv, h, qa, qw, av, lv);
        float align = -(fabsf(av[0]-av[1]) + fabsf(av[0]-av[2]) + fabsf(av[1]-av[2])) * (1.f/3.f);
        float t = (lv[0]*__expf(av[0])*rA0 + lv[1]*__expf(av[1])*rA1 + lv[2]*__expf(av[2])*rA2)
                  * (__expf(align) * rAl);
        beta = __expf(t) * rT;
      }
      int jmax = min(8, deg - c * 8);
      for (int jj = 0; jj < jmax; jj++) {
        float b = __shfl(beta, jj * 8 + hl, 64);
        int s = __shfl(sv, jj * 8, 64);
        size_t base9 = ((size_t)9 * Nsz + s) * 64 + lane;
        unsigned int u0 = Pu[base9];
        unsigned int u1 = Pu[base9 + Nsz * 64];
        unsigned int u2 = Pu[base9 + 2 * Nsz * 64];
        acc00 += b * bf2f((unsigned short)u0); acc01 += b * bf2f((unsigned short)(u0 >> 16));
        acc10 += b * bf2f((unsigned short)u1); acc11 += b * bf2f((unsigned short)(u1 >> 16));
        acc20 += b * bf2f((unsigned short)u2); acc21 += b * bf2f((unsigned short)(u2 >> 16));
      }
    }
  }
  // write this node's 3 hagg rows into the block's LDS tile (row = m*4+wave)
  *(unsigned int*)(&Hs[(0 * 4 + wave) * 136 + 2 * lane]) =
      ((unsigned int)f2bf(acc01) << 16) | f2bf(acc00);
  *(unsigned int*)(&Hs[(1 * 4 + wave) * 136 + 2 * lane]) =
      ((unsigned int)f2bf(acc11) << 16) | f2bf(acc10);
  *(unsigned int*)(&Hs[(2 * 4 + wave) * 136 + 2 * lane]) =
      ((unsigned int)f2bf(acc21) << 16) | f2bf(acc20);
}

// =============== multi-kernel path (primary) ================================
// Dispatch chain: memset -> misc{fold, bucket-scatter} -> proj -> node_out.
__global__ __launch_bounds__(256) void fb_misc(
    const float* Wk, const float* bk, const float* Wq, const float* bq,
    const float* Wv, const float* bv, const float* Wa,
    const float* rel_att, const float* rel_msg, const float* rel_pri,
    const float* wm0, const float* wm1, const float* wm2,
    unsigned short* Wt_all, float* bias_all,
    const int* dst, const int* src, int* counts, int* bucket, int E)
{
  int b = blockIdx.x;
  if (b < 448) {
    int g = b * 256 + threadIdx.x;
    if (g < 7 * 16384)
      fold_item(g, Wk, bk, Wq, bq, Wv, bv, Wa, rel_att, rel_msg, rel_pri,
                wm0, wm1, wm2, Wt_all, bias_all);
  } else {
    int e = (b - 448) * 256 + threadIdx.x;
    if (e < E) {
      int d = dst[e];
      int pos = atomicAdd(&counts[d], 1);
      bucket[(size_t)d * BCAP + (pos & (BCAP - 1))] = src[e];
    }
  }
}

__global__ __launch_bounds__(256) void fb_proj(
    const float* x0, const float* x1, const float* x2,
    const unsigned short* Wt_all, const float* bias_all,
    unsigned short* P, int N)
{
  proj_tile(blockIdx.x, x0, x1, x2, Wt_all, bias_all, P, N, threadIdx.x);
}

// fused node attention + output GEMM. Per block: 4 nodes (1/wave).
// r12: Wa^T B-fragments read directly from L2 (no WtS staging / barrier);
// LDS is just the 8.7KB Hs transpose tile.
__global__ __launch_bounds__(256) void fb_node_out(
    const unsigned short* P, const int* counts, const int* bucket,
    const unsigned short* Wt_all, const float* ba,
    const float* x0, const float* x1, const float* x2, const float* skip,
    float* out, int N)
{
  __shared__ __attribute__((aligned(16))) unsigned short Hs[16 * 136];
  int tid = threadIdx.x, wave = tid >> 6, lane = tid & 63;
  const unsigned short* WaT = Wt_all + (size_t)6 * 16384;
  // zero pad rows 12..15 of Hs (wave w zeroes row 12+w)
  *(unsigned int*)(&Hs[(12 + wave) * 136 + 2 * lane]) = 0u;

  int n = blockIdx.x * 4 + wave;
  if (n < N)
    node_one(n, P, counts, bucket, Hs, N, lane, wave);
  else {
    *(unsigned int*)(&Hs[(0 * 4 + wave) * 136 + 2 * lane]) = 0u;
    *(unsigned int*)(&Hs[(1 * 4 + wave) * 136 + 2 * lane]) = 0u;
    *(unsigned int*)(&Hs[(2 * 4 + wave) * 136 + 2 * lane]) = 0u;
  }
  __syncthreads();

  // out GEMM: rows = Hs (16x128, 12 valid), cols = 128; wave w does col
  // tiles ct = 2w, 2w+1. Swapped MFMA: lane(l16,quad) owns row l16,
  // cols ct*16+quad*4..+3. B-fragments direct from WaT (L2-hot).
  int quad = lane >> 4, l16 = lane & 15;
  floatx4 oacc[2];
  oacc[0] = (floatx4)0.f; oacc[1] = (floatx4)0.f;
#pragma unroll
  for (int kk = 0; kk < 128; kk += 32) {
    uint4 au = *(const uint4*)(&Hs[l16 * 136 + kk + quad * 8]);
    bf16x8 af = __builtin_bit_cast(bf16x8, au);
#pragma unroll
    for (int j = 0; j < 2; j++) {
      int ct = wave * 2 + j;
      uint4 bu = *(const uint4*)(&WaT[(ct * 16 + l16) * 128 + kk + quad * 8]);
      bf16x8 bf = __builtin_bit_cast(bf16x8, bu);
      oacc[j] = __builtin_amdgcn_mfma_f32_16x16x32_bf16(bf, af, oacc[j], 0, 0, 0);
    }
  }
  if (l16 < 12) {
    int m = l16 >> 2, wsrc = l16 & 3;
    int n_out = blockIdx.x * 4 + wsrc;
    if (n_out < N) {
      float alpha = 1.f / (1.f + __expf(-skip[0]));
      float oma = 1.f - alpha;
      const float* X = (m == 0) ? x0 : ((m == 1) ? x1 : x2);
      const float* xr = X + (size_t)n_out * D;
      float* om = out + (size_t)m * N * D + (size_t)n_out * D;
#pragma unroll
      for (int j = 0; j < 2; j++) {
        int colb = (wave * 2 + j) * 16 + quad * 4;
        float4 bi = *(const float4*)(&ba[colb]);
        float4 xv = *(const float4*)(&xr[colb]);
        float4 res;
        res.x = (oacc[j][0] + bi.x) * alpha + xv.x * oma;
        res.y = (oacc[j][1] + bi.y) * alpha + xv.y * oma;
        res.z = (oacc[j][2] + bi.z) * alpha + xv.z * oma;
        res.w = (oacc[j][3] + bi.w) * alpha + xv.w * oma;
        *(float4*)(&om[colb]) = res;
      }
    }
  }
}

// ---------------------------------------------------------------- launch
extern "C" void kernel_launch(void* const* d_in, const int* in_sizes, int n_in,
                              void* d_out, int out_size, void* d_ws, size_t ws_size,
                              hipStream_t stream) {
  const float* x0 = (const float*)d_in[0];
  const float* x1 = (const float*)d_in[1];
  const float* x2 = (const float*)d_in[2];
  const float* Wk = (const float*)d_in[3];
  const float* bk = (const float*)d_in[4];
  const float* Wq = (const float*)d_in[5];
  const float* bq = (const float*)d_in[6];
  const float* Wv = (const float*)d_in[7];
  const float* bv = (const float*)d_in[8];
  const float* Wa = (const float*)d_in[9];
  const float* ba = (const float*)d_in[10];
  const float* rel_att = (const float*)d_in[11];
  const float* rel_msg = (const float*)d_in[12];
  const float* rel_pri = (const float*)d_in[13];
  const float* wm0 = (const float*)d_in[14];
  const float* wm1 = (const float*)d_in[15];
  const float* wm2 = (const float*)d_in[16];
  const float* skip = (const float*)d_in[17];
  const int* src = (const int*)d_in[18];
  const int* dstv = (const int*)d_in[19];
  int N = in_sizes[0] / D;      // 20000
  int E = in_sizes[18];         // 160000

  char* wsb = (char*)d_ws;
  size_t off = 0;
  auto alloc_b = [&](size_t bytes) { size_t o = off; off += (bytes + 63) & ~(size_t)63; return o; };
  unsigned short* P         = (unsigned short*)(wsb + alloc_b((size_t)12 * N * D * 2));
  unsigned short* Wt_all    = (unsigned short*)(wsb + alloc_b((size_t)7 * 16384 * 2));
  float*          bias_all  = (float*)(wsb + alloc_b((size_t)7 * 128 * 4));
  // ctrl: pad[144] | counts[N]
  int*            ctrl      = (int*)(wsb + alloc_b(((size_t)144 + N) * 4));
  int*            bucket    = (int*)(wsb + alloc_b((size_t)N * BCAP * 4));
  int* counts = ctrl + 144;

  // zero counts
  hipMemsetAsync(ctrl, 0, ((size_t)144 + N) * sizeof(int), stream);

  int ntiles = ((N + 63) / 64) * 3;
  fb_misc<<<dim3(448 + (E + 255) / 256), 256, 0, stream>>>(
      Wk, bk, Wq, bq, Wv, bv, Wa, rel_att, rel_msg, rel_pri, wm0, wm1, wm2,
      Wt_all, bias_all, dstv, src, counts, bucket, E);
  fb_proj<<<dim3(ntiles), 256, 0, stream>>>(
      x0, x1, x2, Wt_all, bias_all, P, N);
  fb_node_out<<<dim3((N + 3) / 4), 256, 0, stream>>>(
      P, counts, bucket, Wt_all, ba, x0, x1, x2, skip,
      (float*)d_out, N);
}

// Round 13
// 226.618 us; speedup vs baseline: 1.2052x; 1.2052x over previous
//
#include <hip/hip_runtime.h>

#define D 128
#define NH 8
#define BCAP 64   // per-node edge bucket capacity (E/N=8, Poisson tail << 64)

typedef __bf16 bf16x8 __attribute__((ext_vector_type(8)));
typedef unsigned short ushortx8 __attribute__((ext_vector_type(8)));
typedef float floatx4 __attribute__((ext_vector_type(4)));

__device__ __forceinline__ float bf2f(unsigned short u) {
  union { unsigned int i; float f; } x; x.i = ((unsigned int)u) << 16; return x.f;
}
__device__ __forceinline__ unsigned short f2bf(float f) {
  union { float f; unsigned int i; } x; x.f = f;
  unsigned int i = x.i;
  return (unsigned short)((i + 0x7FFFu + ((i >> 16) & 1u)) >> 16);
}
__device__ __forceinline__ void acc2(unsigned int ku, unsigned int qu, float& s) {
  union { unsigned int i; float f; } a, b;
  a.i = ku << 16;          b.i = qu << 16;          s += a.f * b.f;
  a.i = ku & 0xffff0000u;  b.i = qu & 0xffff0000u;  s += a.f * b.f;
}

// =============== phase helpers (proven bodies) ==============================
// weight fold: p0 Wk ; p1 Wq.rel_attT * pri*2.5 ; p2..4 Wq.wm_mT ; p5 Wv.rel_msg
// p6 = Wa^T bf16 (consumed by the fused node+out GEMM staging).
__device__ __forceinline__ void fold_item(
    int gid,
    const float* __restrict__ Wk, const float* __restrict__ bk,
    const float* __restrict__ Wq, const float* __restrict__ bq,
    const float* __restrict__ Wv, const float* __restrict__ bv,
    const float* __restrict__ Wa,
    const float* __restrict__ rel_att, const float* __restrict__ rel_msg,
    const float* __restrict__ rel_pri,
    const float* __restrict__ wm0, const float* __restrict__ wm1,
    const float* __restrict__ wm2,
    unsigned short* __restrict__ Wt_all, float* __restrict__ bias_all)
{
  int p = gid >> 14;
  int idx = gid & 16383;
  int c = idx >> 7, k = idx & 127;
  int h = c >> 4, r = c & 15;
  float wsum = 0.f, bsum = 0.f;
  if (p == 0) {
    wsum = Wk[k * 128 + c];
    bsum = bk[c];
  } else if (p <= 4) {
    const float* M = (p == 1) ? rel_att : ((p == 2) ? wm0 : ((p == 3) ? wm1 : wm2));
#pragma unroll
    for (int f = 0; f < 16; f++) {
      float mv = M[h * 256 + r * 16 + f];
      wsum += Wq[k * 128 + h * 16 + f] * mv;
      bsum += bq[h * 16 + f] * mv;
    }
    if (p == 1) { float sc = rel_pri[h] * 2.5f; wsum *= sc; bsum *= sc; }
  } else if (p == 5) {
#pragma unroll
    for (int d = 0; d < 16; d++) {
      float mv = rel_msg[h * 256 + d * 16 + r];
      wsum += Wv[k * 128 + h * 16 + d] * mv;
      bsum += bv[h * 16 + d] * mv;
    }
  } else {            // p == 6: Wa^T bf16
    wsum = Wa[k * 128 + c];
    bsum = 0.f;
  }
  Wt_all[(size_t)p * 16384 + c * 128 + k] = f2bf(wsum);
  if (k == 0) bias_all[p * 128 + c] = bsum;
}

// one 64-row x 4-plane projection tile, 256 threads. Full-width LDS staging
// (r9) + swapped MFMA epilogue (r8): lane owns P[row0+l16][ct2*16+quad*4..+3]
// -> dwordx2 stores. NOTE (r12 lesson): the LDS staging is load-LATENCY
// amortization, not bandwidth filtering — de-staging to direct-L2 B-reads
// regressed proj ~40us at this occupancy. Keep the staging.
__device__ __forceinline__ void proj_tile(
    int t, const float* __restrict__ x0, const float* __restrict__ x1,
    const float* __restrict__ x2,
    const unsigned short* __restrict__ Wt_all, const float* __restrict__ bias_all,
    unsigned short* __restrict__ P, int N, unsigned short* Wt, int tid)
{
  int m = t % 3, rt = t / 3;
  const float* X = (m == 0) ? x0 : ((m == 1) ? x1 : x2);
  int wave = tid >> 6, lane = tid & 63;
  int quad = lane >> 4, l16 = lane & 15;
  int row0 = rt * 64 + wave * 16;
  int arow = row0 + l16; if (arow >= N) arow = N - 1;
  const float* ap = X + (size_t)arow * D;
  bf16x8 afr[4];
#pragma unroll
  for (int kk4 = 0; kk4 < 4; kk4++) {
    float4 f0 = *(const float4*)(ap + kk4 * 32 + quad * 8);
    float4 f1 = *(const float4*)(ap + kk4 * 32 + quad * 8 + 4);
    ushortx8 uu;
    uu[0]=f2bf(f0.x); uu[1]=f2bf(f0.y); uu[2]=f2bf(f0.z); uu[3]=f2bf(f0.w);
    uu[4]=f2bf(f1.x); uu[5]=f2bf(f1.y); uu[6]=f2bf(f1.z); uu[7]=f2bf(f1.w);
    afr[kk4] = __builtin_bit_cast(bf16x8, uu);
  }
  int r = row0 + l16;                       // this lane's output row (swapped)
  for (int pt = 0; pt < 4; pt++) {
    int wp = (pt == 0) ? 0 : ((pt == 1) ? 1 : ((pt == 2) ? (2 + m) : 5));
    const unsigned short* Wsrc = Wt_all + (size_t)wp * 16384;
    const float* B = bias_all + wp * 128;
    unsigned short* Pout = P + (size_t)(pt * 3 + m) * N * D;
    __syncthreads();
#pragma unroll
    for (int it = 0; it < 8; it++) {
      int idx = it * 256 + tid;              // 0..2047
      int c = idx >> 4, kc = (idx & 15) << 3;
      *(uint4*)(&Wt[c * 136 + kc]) = *(const uint4*)(&Wsrc[c * 128 + kc]);
    }
    __syncthreads();
    floatx4 acc[8];
#pragma unroll
    for (int ct = 0; ct < 8; ct++) acc[ct] = (floatx4)0.f;
#pragma unroll
    for (int kk4 = 0; kk4 < 4; kk4++) {
#pragma unroll
      for (int ct2 = 0; ct2 < 8; ct2++) {
        uint4 bu = *(const uint4*)(&Wt[(ct2 * 16 + l16) * 136 + kk4 * 32 + quad * 8]);
        bf16x8 bf = __builtin_bit_cast(bf16x8, bu);
        acc[ct2] =
            __builtin_amdgcn_mfma_f32_16x16x32_bf16(bf, afr[kk4], acc[ct2], 0, 0, 0);
      }
    }
    if (r < N) {
      unsigned short* Prow = Pout + (size_t)r * D;
#pragma unroll
      for (int ct2 = 0; ct2 < 8; ct2++) {
        int colb = ct2 * 16 + quad * 4;
        float4 bi = *(const float4*)(&B[colb]);
        unsigned int lo = ((unsigned int)f2bf(acc[ct2][1] + bi.y) << 16) |
                          f2bf(acc[ct2][0] + bi.x);
        unsigned int hi = ((unsigned int)f2bf(acc[ct2][3] + bi.w) << 16) |
                          f2bf(acc[ct2][2] + bi.z);
        uint2 pk; pk.x = lo; pk.y = hi;
        *(uint2*)(&Prow[colb]) = pk;
      }
    }
  }
}

// one dst node per wave — r4-proven body; fetch-traffic-bound at ~2.2TB/s
// random-gather ceiling (r6/r7 falsified occupancy and VMEM-count theories).
// Results go to the block's LDS Hs tile (row = m*4 + wave). Edges come from
// the fixed-capacity bucket (srcs = bucket + n*BCAP).
__device__ __forceinline__ void edge_vals(
    const unsigned short* __restrict__ P, size_t Nsz, int s, int h,
    const uint4 (&qa)[3][2], const uint4 (&qw)[3][2],
    float (&av)[3], float (&lv)[3])
{
#pragma unroll
  for (int m = 0; m < 3; m++) {
    const unsigned short* kp = P + ((size_t)m * Nsz + s) * 128 + h * 16;
    uint4 k0 = *(const uint4*)kp, k1 = *(const uint4*)(kp + 8);
    const unsigned int* ka = (const unsigned int*)&k0;
    const unsigned int* kb = (const unsigned int*)&k1;
    const unsigned int* a0 = (const unsigned int*)&qa[m][0];
    const unsigned int* a1 = (const unsigned int*)&qa[m][1];
    const unsigned int* w0 = (const unsigned int*)&qw[m][0];
    const unsigned int* w1 = (const unsigned int*)&qw[m][1];
    float da = 0.f, dw = 0.f;
#pragma unroll
    for (int j = 0; j < 4; j++) {
      acc2(ka[j], a0[j], da); acc2(kb[j], a1[j], da);
      acc2(ka[j], w0[j], dw); acc2(kb[j], w1[j], dw);
    }
    av[m] = da;
    lv[m] = dw;
  }
  float mx = fmaxf(lv[0], fmaxf(lv[1], lv[2]));
  float e0 = __expf(lv[0] - mx), e1 = __expf(lv[1] - mx), e2 = __expf(lv[2] - mx);
  float inv = 1.f / (e0 + e1 + e2);
  lv[0] = e0 * inv; lv[1] = e1 * inv; lv[2] = e2 * inv;
}

__device__ __forceinline__ void node_one(
    int n, const unsigned short* __restrict__ P,
    const int* __restrict__ counts, const int* __restrict__ bucket,
    unsigned short* __restrict__ Hs,
    int N, int lane, int wave)
{
  const int* srcs = bucket + (size_t)n * BCAP;
  int deg = counts[n]; if (deg > BCAP) deg = BCAP;
  float acc00 = 0, acc01 = 0, acc10 = 0, acc11 = 0, acc20 = 0, acc21 = 0;
  if (deg > 0) {
    int h = lane & 7, slot = lane >> 3;
    size_t Nsz = (size_t)N;
    uint4 qa[3][2], qw[3][2];
#pragma unroll
    for (int m = 0; m < 3; m++) {
      const unsigned short* qap = P + ((size_t)(3 + m) * Nsz + n) * 128 + h * 16;
      const unsigned short* qwp = P + ((size_t)(6 + m) * Nsz + n) * 128 + h * 16;
      qa[m][0] = *(const uint4*)qap; qa[m][1] = *(const uint4*)(qap + 8);
      qw[m][0] = *(const uint4*)qwp; qw[m][1] = *(const uint4*)(qwp + 8);
    }
    int nch = (deg + 7) >> 3;
    float cX0[4] = {}, cX1[4] = {}, cX2[4] = {}, cEa[4] = {}, cT[4] = {};
    int cS[4] = {};
    float sA0 = 0, sA1 = 0, sA2 = 0, sAl = 0;
#pragma unroll
    for (int c = 0; c < 4; c++) {
      int idx = c * 8 + slot;
      if (c < nch && idx < deg) {
        int s = srcs[idx]; cS[c] = s;
        float av[3], lv[3];
        edge_vals(P, Nsz, s, h, qa, qw, av, lv);
        float e0 = __expf(av[0]), e1 = __expf(av[1]), e2 = __expf(av[2]);
        float align = -(fabsf(av[0]-av[1]) + fabsf(av[0]-av[2]) + fabsf(av[1]-av[2])) * (1.f/3.f);
        float ea = __expf(align);
        cX0[c] = lv[0] * e0; cX1[c] = lv[1] * e1; cX2[c] = lv[2] * e2; cEa[c] = ea;
        sA0 += e0; sA1 += e1; sA2 += e2; sAl += ea;
      }
    }
    for (int c = 4; c < nch; c++) {
      int idx = c * 8 + slot;
      if (idx < deg) {
        int s = srcs[idx];
        float av[3], lv[3];
        edge_vals(P, Nsz, s, h, qa, qw, av, lv);
        float align = -(fabsf(av[0]-av[1]) + fabsf(av[0]-av[2]) + fabsf(av[1]-av[2])) * (1.f/3.f);
        sA0 += __expf(av[0]); sA1 += __expf(av[1]); sA2 += __expf(av[2]);
        sAl += __expf(align);
      }
    }
#pragma unroll
    for (int off = 8; off < 64; off <<= 1) {
      sA0 += __shfl_xor(sA0, off, 64);
      sA1 += __shfl_xor(sA1, off, 64);
      sA2 += __shfl_xor(sA2, off, 64);
      sAl += __shfl_xor(sAl, off, 64);
    }
    float rA0 = 1.f / fmaxf(sA0, 1e-30f), rA1 = 1.f / fmaxf(sA1, 1e-30f);
    float rA2 = 1.f / fmaxf(sA2, 1e-30f), rAl = 1.f / fmaxf(sAl, 1e-30f);
    float sT = 0;
#pragma unroll
    for (int c = 0; c < 4; c++) {
      int idx = c * 8 + slot;
      if (c < nch && idx < deg) {
        float t = (cX0[c] * rA0 + cX1[c] * rA1 + cX2[c] * rA2) * (cEa[c] * rAl);
        cT[c] = t;
        sT += __expf(t);
      }
    }
    for (int c = 4; c < nch; c++) {
      int idx = c * 8 + slot;
      if (idx < deg) {
        int s = srcs[idx];
        float av[3], lv[3];
        edge_vals(P, Nsz, s, h, qa, qw, av, lv);
        float align = -(fabsf(av[0]-av[1]) + fabsf(av[0]-av[2]) + fabsf(av[1]-av[2])) * (1.f/3.f);
        float t = (lv[0]*__expf(av[0])*rA0 + lv[1]*__expf(av[1])*rA1 + lv[2]*__expf(av[2])*rA2)
                  * (__expf(align) * rAl);
        sT += __expf(t);
      }
    }
#pragma unroll
    for (int off = 8; off < 64; off <<= 1) sT += __shfl_xor(sT, off, 64);
    float rT = 1.f / fmaxf(sT, 1e-30f);
    const unsigned int* Pu = (const unsigned int*)P;
    int hl = lane >> 3;
#pragma unroll
    for (int c = 0; c < 4; c++) {
      if (c < nch) {
        int idx = c * 8 + slot;
        float beta = (idx < deg) ? __expf(cT[c]) * rT : 0.f;
        int sv = cS[c];
        float bj[8]; int sj[8];
#pragma unroll
        for (int jj = 0; jj < 8; jj++) {
          bj[jj] = __shfl(beta, jj * 8 + hl, 64);
          sj[jj] = __shfl(sv, jj * 8, 64);
        }
#pragma unroll
        for (int jj = 0; jj < 8; jj++) {
          size_t base9 = ((size_t)9 * Nsz + sj[jj]) * 64 + lane;
          unsigned int u0 = Pu[base9];
          unsigned int u1 = Pu[base9 + Nsz * 64];
          unsigned int u2 = Pu[base9 + 2 * Nsz * 64];
          float b = bj[jj];
          acc00 += b * bf2f((unsigned short)u0); acc01 += b * bf2f((unsigned short)(u0 >> 16));
          acc10 += b * bf2f((unsigned short)u1); acc11 += b * bf2f((unsigned short)(u1 >> 16));
          acc20 += b * bf2f((unsigned short)u2); acc21 += b * bf2f((unsigned short)(u2 >> 16));
        }
      }
    }
    for (int c = 4; c < nch; c++) {
      int idx = c * 8 + slot;
      float beta = 0.f; int sv = 0;
      if (idx < deg) {
        sv = srcs[idx];
        float av[3], lv[3];
        edge_vals(P, Nsz, sv, h, qa, qw, av, lv);
        float align = -(fabsf(av[0]-av[1]) + fabsf(av[0]-av[2]) + fabsf(av[1]-av[2])) * (1.f/3.f);
        float t = (lv[0]*__expf(av[0])*rA0 + lv[1]*__expf(av[1])*rA1 + lv[2]*__expf(av[2])*rA2)
                  * (__expf(align) * rAl);
        beta = __expf(t) * rT;
      }
      int jmax = min(8, deg - c * 8);
      for (int jj = 0; jj < jmax; jj++) {
        float b = __shfl(beta, jj * 8 + hl, 64);
        int s = __shfl(sv, jj * 8, 64);
        size_t base9 = ((size_t)9 * Nsz + s) * 64 + lane;
        unsigned int u0 = Pu[base9];
        unsigned int u1 = Pu[base9 + Nsz * 64];
        unsigned int u2 = Pu[base9 + 2 * Nsz * 64];
        acc00 += b * bf2f((unsigned short)u0); acc01 += b * bf2f((unsigned short)(u0 >> 16));
        acc10 += b * bf2f((unsigned short)u1); acc11 += b * bf2f((unsigned short)(u1 >> 16));
        acc20 += b * bf2f((unsigned short)u2); acc21 += b * bf2f((unsigned short)(u2 >> 16));
      }
    }
  }
  // write this node's 3 hagg rows into the block's LDS tile (row = m*4+wave)
  *(unsigned int*)(&Hs[(0 * 4 + wave) * 136 + 2 * lane]) =
      ((unsigned int)f2bf(acc01) << 16) | f2bf(acc00);
  *(unsigned int*)(&Hs[(1 * 4 + wave) * 136 + 2 * lane]) =
      ((unsigned int)f2bf(acc11) << 16) | f2bf(acc10);
  *(unsigned int*)(&Hs[(2 * 4 + wave) * 136 + 2 * lane]) =
      ((unsigned int)f2bf(acc21) << 16) | f2bf(acc20);
}

// =============== multi-kernel path (primary) ================================
// Dispatch chain: memset -> misc{fold, bucket-scatter} -> proj -> node_out.
__global__ __launch_bounds__(256) void fb_misc(
    const float* Wk, const float* bk, const float* Wq, const float* bq,
    const float* Wv, const float* bv, const float* Wa,
    const float* rel_att, const float* rel_msg, const float* rel_pri,
    const float* wm0, const float* wm1, const float* wm2,
    unsigned short* Wt_all, float* bias_all,
    const int* dst, const int* src, int* counts, int* bucket, int E)
{
  int b = blockIdx.x;
  if (b < 448) {
    int g = b * 256 + threadIdx.x;
    if (g < 7 * 16384)
      fold_item(g, Wk, bk, Wq, bq, Wv, bv, Wa, rel_att, rel_msg, rel_pri,
                wm0, wm1, wm2, Wt_all, bias_all);
  } else {
    int e = (b - 448) * 256 + threadIdx.x;
    if (e < E) {
      int d = dst[e];
      int pos = atomicAdd(&counts[d], 1);
      bucket[(size_t)d * BCAP + (pos & (BCAP - 1))] = src[e];
    }
  }
}

__global__ __launch_bounds__(256) void fb_proj(
    const float* x0, const float* x1, const float* x2,
    const unsigned short* Wt_all, const float* bias_all,
    unsigned short* P, int N)
{
  __shared__ __attribute__((aligned(16))) unsigned short Wt[128 * 136];
  proj_tile(blockIdx.x, x0, x1, x2, Wt_all, bias_all, P, N, Wt, threadIdx.x);
}

// fused node attention + output GEMM (r10/r11 proven form). Per block:
// 4 nodes (1/wave). Wa^T staged in LDS (r12 lesson: staging = latency
// amortization; direct-L2 B-reads regress at this occupancy).
__global__ __launch_bounds__(256) void fb_node_out(
    const unsigned short* P, const int* counts, const int* bucket,
    const unsigned short* Wt_all, const float* ba,
    const float* x0, const float* x1, const float* x2, const float* skip,
    float* out, int N)
{
  __shared__ __attribute__((aligned(16))) unsigned short WtS[128 * 136];
  __shared__ __attribute__((aligned(16))) unsigned short Hs[16 * 136];
  int tid = threadIdx.x, wave = tid >> 6, lane = tid & 63;
  // stage Wa^T (bf16, [col][k]) — pure uint4 copies from Wt_all plane 6
  const unsigned short* WaT = Wt_all + (size_t)6 * 16384;
#pragma unroll
  for (int it = 0; it < 8; it++) {
    int idx = it * 256 + tid;
    int c = idx >> 4, kc = (idx & 15) << 3;
    *(uint4*)(&WtS[c * 136 + kc]) = *(const uint4*)(&WaT[c * 128 + kc]);
  }
  // zero pad rows 12..15 of Hs (wave w zeroes row 12+w)
  *(unsigned int*)(&Hs[(12 + wave) * 136 + 2 * lane]) = 0u;

  int n = blockIdx.x * 4 + wave;
  if (n < N)
    node_one(n, P, counts, bucket, Hs, N, lane, wave);
  else {
    *(unsigned int*)(&Hs[(0 * 4 + wave) * 136 + 2 * lane]) = 0u;
    *(unsigned int*)(&Hs[(1 * 4 + wave) * 136 + 2 * lane]) = 0u;
    *(unsigned int*)(&Hs[(2 * 4 + wave) * 136 + 2 * lane]) = 0u;
  }
  __syncthreads();

  // out GEMM: rows = Hs (16x128, 12 valid), cols = 128; wave w does col
  // tiles ct = 2w, 2w+1. Swapped MFMA: lane(l16,quad) owns row l16,
  // cols ct*16+quad*4..+3.
  int quad = lane >> 4, l16 = lane & 15;
  floatx4 oacc[2];
  oacc[0] = (floatx4)0.f; oacc[1] = (floatx4)0.f;
#pragma unroll
  for (int kk = 0; kk < 128; kk += 32) {
    uint4 au = *(const uint4*)(&Hs[l16 * 136 + kk + quad * 8]);
    bf16x8 af = __builtin_bit_cast(bf16x8, au);
#pragma unroll
    for (int j = 0; j < 2; j++) {
      int ct = wave * 2 + j;
      uint4 bu = *(const uint4*)(&WtS[(ct * 16 + l16) * 136 + kk + quad * 8]);
      bf16x8 bf = __builtin_bit_cast(bf16x8, bu);
      oacc[j] = __builtin_amdgcn_mfma_f32_16x16x32_bf16(bf, af, oacc[j], 0, 0, 0);
    }
  }
  if (l16 < 12) {
    int m = l16 >> 2, wsrc = l16 & 3;
    int n_out = blockIdx.x * 4 + wsrc;
    if (n_out < N) {
      float alpha = 1.f / (1.f + __expf(-skip[0]));
      float oma = 1.f - alpha;
      const float* X = (m == 0) ? x0 : ((m == 1) ? x1 : x2);
      const float* xr = X + (size_t)n_out * D;
      float* om = out + (size_t)m * N * D + (size_t)n_out * D;
#pragma unroll
      for (int j = 0; j < 2; j++) {
        int colb = (wave * 2 + j) * 16 + quad * 4;
        float4 bi = *(const float4*)(&ba[colb]);
        float4 xv = *(const float4*)(&xr[colb]);
        float4 res;
        res.x = (oacc[j][0] + bi.x) * alpha + xv.x * oma;
        res.y = (oacc[j][1] + bi.y) * alpha + xv.y * oma;
        res.z = (oacc[j][2] + bi.z) * alpha + xv.z * oma;
        res.w = (oacc[j][3] + bi.w) * alpha + xv.w * oma;
        *(float4*)(&om[colb]) = res;
      }
    }
  }
}

// ---------------------------------------------------------------- launch
extern "C" void kernel_launch(void* const* d_in, const int* in_sizes, int n_in,
                              void* d_out, int out_size, void* d_ws, size_t ws_size,
                              hipStream_t stream) {
  const float* x0 = (const float*)d_in[0];
  const float* x1 = (const float*)d_in[1];
  const float* x2 = (const float*)d_in[2];
  const float* Wk = (const float*)d_in[3];
  const float* bk = (const float*)d_in[4];
  const float* Wq = (const float*)d_in[5];
  const float* bq = (const float*)d_in[6];
  const float* Wv = (const float*)d_in[7];
  const float* bv = (const float*)d_in[8];
  const float* Wa = (const float*)d_in[9];
  const float* ba = (const float*)d_in[10];
  const float* rel_att = (const float*)d_in[11];
  const float* rel_msg = (const float*)d_in[12];
  const float* rel_pri = (const float*)d_in[13];
  const float* wm0 = (const float*)d_in[14];
  const float* wm1 = (const float*)d_in[15];
  const float* wm2 = (const float*)d_in[16];
  const float* skip = (const float*)d_in[17];
  const int* src = (const int*)d_in[18];
  const int* dstv = (const int*)d_in[19];
  int N = in_sizes[0] / D;      // 20000
  int E = in_sizes[18];         // 160000

  char* wsb = (char*)d_ws;
  size_t off = 0;
  auto alloc_b = [&](size_t bytes) { size_t o = off; off += (bytes + 63) & ~(size_t)63; return o; };
  unsigned short* P         = (unsigned short*)(wsb + alloc_b((size_t)12 * N * D * 2));
  unsigned short* Wt_all    = (unsigned short*)(wsb + alloc_b((size_t)7 * 16384 * 2));
  float*          bias_all  = (float*)(wsb + alloc_b((size_t)7 * 128 * 4));
  // ctrl: pad[144] | counts[N]
  int*            ctrl      = (int*)(wsb + alloc_b(((size_t)144 + N) * 4));
  int*            bucket    = (int*)(wsb + alloc_b((size_t)N * BCAP * 4));
  int* counts = ctrl + 144;

  // zero counts
  hipMemsetAsync(ctrl, 0, ((size_t)144 + N) * sizeof(int), stream);

  int ntiles = ((N + 63) / 64) * 3;
  fb_misc<<<dim3(448 + (E + 255) / 256), 256, 0, stream>>>(
      Wk, bk, Wq, bq, Wv, bv, Wa, rel_att, rel_msg, rel_pri, wm0, wm1, wm2,
      Wt_all, bias_all, dstv, src, counts, bucket, E);
  fb_proj<<<dim3(ntiles), 256, 0, stream>>>(
      x0, x1, x2, Wt_all, bias_all, P, N);
  fb_node_out<<<dim3((N + 3) / 4), 256, 0, stream>>>(
      P, counts, bucket, Wt_all, ba, x0, x1, x2, skip,
      (float*)d_out, N);
}